// Round 2
// baseline (25.573 us; speedup 1.0000x reference)
//
#include <hip/hip_runtime.h>

// Polyphase resampler, up=2 / down=3, FILT=128 taps, fp32.
//   out[2g]   = 2 * sum_{m=0..63} x[31+3g-m] * f[2m+1]
//   out[2g+1] = 2 * sum_{m=0..63} x[33+3g-m] * f[2m]
// x zero-extended outside [0,N). out_len = ceil(2N/3).
//
// R2: LDS-staged x (coalesced float4 global loads) + XOR-swizzled
// ds_read_b128 window reads. R1 was VMEM-request-bound (96B lane stride).

constexpr int R       = 8;                 // output pairs per thread
constexpr int BT      = 256;               // threads per block
constexpr int PPB     = R * BT;            // 2048 pairs per block
constexpr int XFLOATS = 3 * PPB + 64;      // 6208 staged x floats per block
constexpr int XVEC4   = XFLOATS / 4;       // 1552 float4 chunks
constexpr int XBYTES  = XFLOATS * 4;       // 24832 B
constexpr int WIN     = 88;                // per-thread register window (87 used)

// XOR slot swizzle: permutes 16B slots within each 128B row group.
// Staging writes (16B lane stride) stay conflict-free; window reads
// (96B lane stride, else 16-way conflict) become balanced ~8 lanes/slot.
__device__ __forceinline__ int swz(int byte) {
    return byte ^ (((byte >> 7) & 7) << 4);
}

__global__ __launch_bounds__(BT) void resample23_kernel(
    const float* __restrict__ x,
    const float* __restrict__ filt,
    float* __restrict__ out,
    int N, int out_size)
{
    __shared__ float fs[128];                          // fs[k] = 2*f[k]
    __shared__ __align__(16) unsigned char xs[XBYTES]; // swizzled x tile

    const int t = threadIdx.x;
    if (t < 128) fs[t] = 2.0f * filt[t];

    const int g0    = blockIdx.x * PPB;
    const int gbase = 3 * g0 - 32;        // global float idx of xs linear 0; %4==0

    // ---- stage x tile: coalesced float4 loads -> swizzled LDS writes ----
    #pragma unroll
    for (int k = 0; k < (XVEC4 + BT - 1) / BT; ++k) {
        int idx = t + BT * k;
        if (idx < XVEC4) {
            int f0 = gbase + 4 * idx;
            float4 v;
            if (f0 >= 0 && f0 + 4 <= N) {
                v = *reinterpret_cast<const float4*>(x + f0);
            } else {
                v.x = (f0 + 0 >= 0 && f0 + 0 < N) ? x[f0 + 0] : 0.0f;
                v.y = (f0 + 1 >= 0 && f0 + 1 < N) ? x[f0 + 1] : 0.0f;
                v.z = (f0 + 2 >= 0 && f0 + 2 < N) ? x[f0 + 2] : 0.0f;
                v.w = (f0 + 3 >= 0 && f0 + 3 < N) ? x[f0 + 3] : 0.0f;
            }
            *reinterpret_cast<float4*>(xs + swz(16 * idx)) = v;
        }
    }
    __syncthreads();

    // ---- read per-thread 88-float window from LDS (swizzled b128) ----
    float xr[WIN];
    #pragma unroll
    for (int i = 0; i < WIN / 4; ++i) {
        float4 v = *reinterpret_cast<const float4*>(xs + swz(96 * t + 16 * i));
        xr[4*i+0] = v.x; xr[4*i+1] = v.y; xr[4*i+2] = v.z; xr[4*i+3] = v.w;
    }

    // ---- polyphase FIR: 64 taps per phase, 2 phases, R pairs ----
    float acc[2 * R];
    #pragma unroll
    for (int i = 0; i < 2 * R; ++i) acc[i] = 0.0f;

    #pragma unroll
    for (int mm = 0; mm < 32; ++mm) {     // two taps (m0,m1) per iteration
        float4 c = *reinterpret_cast<const float4*>(&fs[4 * mm]);
        // c.x=2f[4mm]  c.y=2f[4mm+1]  c.z=2f[4mm+2]  c.w=2f[4mm+3]
        const int m0 = 2 * mm, m1 = 2 * mm + 1;
        #pragma unroll
        for (int p = 0; p < R; ++p) {
            acc[2*p]     += xr[63 - m0 + 3*p] * c.y;   // even output, f[2m0+1]
            acc[2*p + 1] += xr[65 - m0 + 3*p] * c.x;   // odd  output, f[2m0]
            acc[2*p]     += xr[63 - m1 + 3*p] * c.w;   // even output, f[2m1+1]
            acc[2*p + 1] += xr[65 - m1 + 3*p] * c.z;   // odd  output, f[2m1]
        }
    }

    // ---- store 16 contiguous outputs ----
    const int j0 = 2 * (g0 + t * R);
    if (j0 + 2 * R <= out_size) {
        float4* ov = reinterpret_cast<float4*>(out + j0);
        #pragma unroll
        for (int q = 0; q < (2 * R) / 4; ++q)
            ov[q] = make_float4(acc[4*q], acc[4*q+1], acc[4*q+2], acc[4*q+3]);
    } else {
        #pragma unroll
        for (int i = 0; i < 2 * R; ++i)
            if (j0 + i < out_size) out[j0 + i] = acc[i];
    }
}

extern "C" void kernel_launch(void* const* d_in, const int* in_sizes, int n_in,
                              void* d_out, int out_size, void* d_ws, size_t ws_size,
                              hipStream_t stream)
{
    const float* x    = (const float*)d_in[0];
    const float* filt = (const float*)d_in[1];
    float* out        = (float*)d_out;
    const int N       = in_sizes[0];

    const int n_pairs = (out_size + 1) / 2;
    const int blocks  = (n_pairs + PPB - 1) / PPB;
    resample23_kernel<<<blocks, BT, 0, stream>>>(x, filt, out, N, out_size);
}